// Round 3
// baseline (670.495 us; speedup 1.0000x reference)
//
#include <hip/hip_runtime.h>

// B=4, S=1024, EMB=1024, H=16, HD=64, MAXP=512
// Outputs (float32, concatenated): out0 [4,1024,1024] (4,194,304), attn [64,1024,1024] (67,108,864)

using s16x8 = __attribute__((ext_vector_type(8))) short;
using f32x4 = __attribute__((ext_vector_type(4))) float;

#define MFMA16 __builtin_amdgcn_mfma_f32_16x16x32_bf16

__device__ __forceinline__ float bf2f(unsigned short u) {
  union { unsigned int u; float f; } v; v.u = ((unsigned int)u) << 16; return v.f;
}
__device__ __forceinline__ unsigned short f2bf(float f) {
  union { float f; unsigned int u; } v; v.f = f;
  unsigned int r = (v.u + 0x7FFFu + ((v.u >> 16) & 1u)) >> 16;
  return (unsigned short)r;
}

// ---------- fp32 -> bf16, 8 elems/thread ----------
__global__ void k_cvt_bf16(const float* __restrict__ in, unsigned short* __restrict__ out, int n) {
  int i = (blockIdx.x * 256 + threadIdx.x) * 8;
  if (i >= n) return;
  float4 a = *(const float4*)(in + i);
  float4 b = *(const float4*)(in + i + 4);
  s16x8 o;
  o[0] = (short)f2bf(a.x); o[1] = (short)f2bf(a.y); o[2] = (short)f2bf(a.z); o[3] = (short)f2bf(a.w);
  o[4] = (short)f2bf(b.x); o[5] = (short)f2bf(b.y); o[6] = (short)f2bf(b.z); o[7] = (short)f2bf(b.w);
  *(s16x8*)(out + i) = o;
}

// ---------- 1024x1024 transpose + cvt: Wt[n][k] = W[k][n] ----------
__global__ void k_tr1024(const float* __restrict__ W, unsigned short* __restrict__ Wt) {
  __shared__ float t[32][33];
  int tx = threadIdx.x, ty = threadIdx.y;           // 32 x 8
  int n0 = blockIdx.x * 32, k0 = blockIdx.y * 32;
#pragma unroll
  for (int r = 0; r < 4; ++r)
    t[ty * 4 + r][tx] = W[(size_t)(k0 + ty * 4 + r) * 1024 + n0 + tx];
  __syncthreads();
#pragma unroll
  for (int r = 0; r < 4; ++r)
    Wt[(size_t)(n0 + ty * 4 + r) * 1024 + k0 + tx] = f2bf(t[tx][ty * 4 + r]);
}

// ---------- rel_v transpose: rvT[d][p] (row stride 1040) ----------
__global__ void k_relvT(const float* __restrict__ rv, unsigned short* __restrict__ rvT) {
  int i = blockIdx.x * 256 + threadIdx.x;
  if (i >= 1025 * 64) return;
  int p = i >> 6, d = i & 63;
  rvT[d * 1040 + p] = f2bf(rv[i]);
}

// ---------- bf16 GEMM: C[4096x1024] = A[4096x1024] @ BT[1024x1024]^T + bias ----------
// MODE 0: store bf16 to per-head layout [bh][s][d] ; MODE 1: store float32 row-major
template <int MODE>
__global__ __launch_bounds__(256, 2)
void k_gemm(const unsigned short* __restrict__ A, const unsigned short* __restrict__ BT,
            const float* __restrict__ bias, void* __restrict__ Cout) {
  __shared__ alignas(16) unsigned short aT[2][4096];
  __shared__ alignas(16) unsigned short bT[2][4096];
  const int tid = threadIdx.x;
  const int lane = tid & 63;
  const int l15 = lane & 15, lhi = lane >> 4;
  const int w = tid >> 6;
  const int wr = (w >> 1) * 64, wc = (w & 1) * 64;
  const int brow = blockIdx.y * 128, bcol = blockIdx.x * 128;
  f32x4 acc[4][4] = {};

#define STAGE(buf, kt) do {                                                              \
    int k0s = (kt) * 32;                                                                 \
    {                                                                                    \
      int c = tid;                                                                       \
      int row = c >> 2, k8 = (c & 3) * 8;                                                \
      __builtin_amdgcn_global_load_lds(                                                  \
        (const __attribute__((address_space(1))) void*)(A + (size_t)(brow + row) * 1024 + k0s + k8), \
        (__attribute__((address_space(3))) void*)(&aT[buf][c * 8]), 16, 0, 0);           \
      __builtin_amdgcn_global_load_lds(                                                  \
        (const __attribute__((address_space(1))) void*)(BT + (size_t)(bcol + row) * 1024 + k0s + k8),\
        (__attribute__((address_space(3))) void*)(&bT[buf][c * 8]), 16, 0, 0);           \
    }                                                                                    \
    {                                                                                    \
      int c = tid + 256;                                                                 \
      int row = c >> 2, k8 = (c & 3) * 8;                                                \
      __builtin_amdgcn_global_load_lds(                                                  \
        (const __attribute__((address_space(1))) void*)(A + (size_t)(brow + row) * 1024 + k0s + k8), \
        (__attribute__((address_space(3))) void*)(&aT[buf][c * 8]), 16, 0, 0);           \
      __builtin_amdgcn_global_load_lds(                                                  \
        (const __attribute__((address_space(1))) void*)(BT + (size_t)(bcol + row) * 1024 + k0s + k8),\
        (__attribute__((address_space(3))) void*)(&bT[buf][c * 8]), 16, 0, 0);           \
    }                                                                                    \
  } while (0)

  int cur = 0;
  STAGE(0, 0);
  for (int kt = 0; kt < 32; ++kt) {
    __syncthreads();                       // drains vmcnt: buf[cur] ready
    if (kt + 1 < 32) STAGE(cur ^ 1, kt + 1);
    s16x8 af[4], bfv[4];
#pragma unroll
    for (int m = 0; m < 4; ++m)
      af[m] = *(const s16x8*)&aT[cur][(wr + m * 16 + l15) * 32 + lhi * 8];
#pragma unroll
    for (int n = 0; n < 4; ++n)
      bfv[n] = *(const s16x8*)&bT[cur][(wc + n * 16 + l15) * 32 + lhi * 8];
#pragma unroll
    for (int m = 0; m < 4; ++m)
#pragma unroll
      for (int n = 0; n < 4; ++n)
        acc[m][n] = MFMA16(af[m], bfv[n], acc[m][n], 0, 0, 0);
    __syncthreads();
    cur ^= 1;
  }
#undef STAGE

#pragma unroll
  for (int m = 0; m < 4; ++m) {
#pragma unroll
    for (int n = 0; n < 4; ++n) {
      int col = bcol + wc + n * 16 + l15;
      float bs = bias[col];
#pragma unroll
      for (int j = 0; j < 4; ++j) {
        int r = brow + wr + m * 16 + lhi * 4 + j;
        float v = acc[m][n][j] + bs;
        if (MODE == 0) {
          int b = r >> 10, s = r & 1023, h = col >> 6, d = col & 63;
          ((unsigned short*)Cout)[(((size_t)((b << 4) + h) * 1024 + s) << 6) + d] = f2bf(v);
        } else {
          ((float*)Cout)[(size_t)r * 1024 + col] = v;
        }
      }
    }
  }
}

// ---------- fused attention ----------
#define RPW 1032   // p-buffer row stride (elems)
#define VTP 72     // V^T row stride
#define WSP 96     // shear window stride
#define RVP 104    // rel_v window stride

__global__ __launch_bounds__(256, 2)
void k_attn(const unsigned short* __restrict__ qb, const unsigned short* __restrict__ kbm,
            const unsigned short* __restrict__ vbm, const unsigned short* __restrict__ relk,
            const unsigned short* __restrict__ rvT, float* __restrict__ attn_out,
            unsigned short* __restrict__ xscr) {
  __shared__ alignas(16) unsigned short pbuf[16 * RPW];   // unnormalized exp, bf16
  __shared__ alignas(16) unsigned short Vt[64 * VTP];     // V^T chunk
  __shared__ alignas(16) unsigned short Wsh[16 * WSP];    // sheared p window
  __shared__ alignas(16) unsigned short RVt[64 * RVP];    // rel_v^T window
  __shared__ float redM[4][16], redZ[4][16], m16[16], iz16[16];

  const int tid = threadIdx.x;
  const int lane = tid & 63;
  const int w = tid >> 6;
  const int l15 = lane & 15, lhi = lane >> 4;
  const int bh = blockIdx.x >> 6;
  const int q0 = (blockIdx.x & 63) << 4;

  const unsigned short* Qh = qb + ((size_t)bh << 16);
  const unsigned short* Kh = kbm + ((size_t)bh << 16);
  const unsigned short* Vh = vbm + ((size_t)bh << 16);

  const unsigned short* qp = Qh + (size_t)(q0 + l15) * 64 + lhi * 8;
  s16x8 qa0 = *(const s16x8*)qp;
  s16x8 qa1 = *(const s16x8*)(qp + 32);

  // ---- pass A: row max of raw qk (|rel|/8 small, safe to ignore for the max) ----
  float vmax[4] = {-3e38f, -3e38f, -3e38f, -3e38f};
  for (int k0 = w * 16; k0 < 1024; k0 += 64) {
    const unsigned short* kp = Kh + (size_t)(k0 + l15) * 64 + lhi * 8;
    s16x8 kf0 = *(const s16x8*)kp;
    s16x8 kf1 = *(const s16x8*)(kp + 32);
    f32x4 c = {0.f, 0.f, 0.f, 0.f};
    c = MFMA16(qa0, kf0, c, 0, 0, 0);
    c = MFMA16(qa1, kf1, c, 0, 0, 0);
#pragma unroll
    for (int j = 0; j < 4; ++j) vmax[j] = fmaxf(vmax[j], c[j]);
  }
#pragma unroll
  for (int off = 1; off < 16; off <<= 1)
#pragma unroll
    for (int j = 0; j < 4; ++j) vmax[j] = fmaxf(vmax[j], __shfl_xor(vmax[j], off, 64));
  if (l15 == 0) {
#pragma unroll
    for (int j = 0; j < 4; ++j) redM[w][lhi * 4 + j] = vmax[j];
  }
  __syncthreads();
  if (tid < 16)
    m16[tid] = fmaxf(fmaxf(redM[0][tid], redM[1][tid]), fmaxf(redM[2][tid], redM[3][tid])) * 0.125f;
  __syncthreads();
  float mrow[4];
#pragma unroll
  for (int j = 0; j < 4; ++j) mrow[j] = m16[lhi * 4 + j];

  // ---- pass B: logits = (qk + rel)/8 ; rel via 32-wide window MFMA + in-group shuffle ----
  float zp[4] = {0.f, 0.f, 0.f, 0.f};
  for (int k0 = w * 16; k0 < 1024; k0 += 64) {
    const unsigned short* kp = Kh + (size_t)(k0 + l15) * 64 + lhi * 8;
    s16x8 kf0 = *(const s16x8*)kp;
    s16x8 kf1 = *(const s16x8*)(kp + 32);
    f32x4 c = {0.f, 0.f, 0.f, 0.f};
    c = MFMA16(qa0, kf0, c, 0, 0, 0);
    c = MFMA16(qa1, kf1, c, 0, 0, 0);
    const int jb = k0 - q0 - 15;
    int p0 = jb + l15;      p0 = (p0 < -512 ? -512 : (p0 > 512 ? 512 : p0)) + 512;
    int p1 = jb + l15 + 16; p1 = (p1 < -512 ? -512 : (p1 > 512 ? 512 : p1)) + 512;
    const unsigned short* r0p = relk + (size_t)p0 * 64 + lhi * 8;
    const unsigned short* r1p = relk + (size_t)p1 * 64 + lhi * 8;
    s16x8 ra0 = *(const s16x8*)r0p, ra0h = *(const s16x8*)(r0p + 32);
    s16x8 ra1 = *(const s16x8*)r1p, ra1h = *(const s16x8*)(r1p + 32);
    f32x4 w0 = {0.f, 0.f, 0.f, 0.f}, w1 = {0.f, 0.f, 0.f, 0.f};
    w0 = MFMA16(qa0, ra0, w0, 0, 0, 0);  w0 = MFMA16(qa1, ra0h, w0, 0, 0, 0);
    w1 = MFMA16(qa0, ra1, w1, 0, 0, 0);  w1 = MFMA16(qa1, ra1h, w1, 0, 0, 0);
#pragma unroll
    for (int j = 0; j < 4; ++j) {
      int qi = lhi * 4 + j;
      int ts = l15 - qi + 15;                 // [0,30]
      int sl = (lane & 48) | (ts & 15);
      float a0 = __shfl(w0[j], sl, 64);
      float a1 = __shfl(w1[j], sl, 64);
      float rel = (ts & 16) ? a1 : a0;
      float e = __expf((c[j] + rel) * 0.125f - mrow[j]);
      zp[j] += e;
      pbuf[qi * RPW + k0 + l15] = f2bf(e);
    }
  }
#pragma unroll
  for (int off = 1; off < 16; off <<= 1)
#pragma unroll
    for (int j = 0; j < 4; ++j) zp[j] += __shfl_xor(zp[j], off, 64);
  if (l15 == 0) {
#pragma unroll
    for (int j = 0; j < 4; ++j) redZ[w][lhi * 4 + j] = zp[j];
  }
  __syncthreads();
  if (tid < 16)
    iz16[tid] = 1.0f / (redZ[0][tid] + redZ[1][tid] + redZ[2][tid] + redZ[3][tid]);
  __syncthreads();

  // ---- pass C: normalized attn -> d_out (float32, coalesced) ----
  {
    float* ao = attn_out + ((size_t)bh << 20) + ((size_t)q0 << 10);
    for (int idx = tid; idx < 16384; idx += 256) {
      int r = idx >> 10;
      ao[idx] = bf2f(pbuf[r * RPW + (idx & 1023)]) * iz16[r];
    }
  }

  // ---- PV + rel_v (sheared window GEMM); final scale by 1/Z ----
  f32x4 acc = {0.f, 0.f, 0.f, 0.f};
  const int d0w = w << 4;
  for (int k0 = 0; k0 < 1024; k0 += 64) {
    __syncthreads();
    {  // stage V^T chunk [64d][64k]
      int kk = tid >> 2, cb = (tid & 3) << 4;
      const unsigned short* vs = Vh + (size_t)(k0 + kk) * 64 + cb;
      s16x8 v0 = *(const s16x8*)vs;
      s16x8 v1 = *(const s16x8*)(vs + 8);
#pragma unroll
      for (int e = 0; e < 8; ++e) Vt[(cb + e) * VTP + kk] = (unsigned short)v0[e];
#pragma unroll
      for (int e = 0; e < 8; ++e) Vt[(cb + 8 + e) * VTP + kk] = (unsigned short)v1[e];
    }
    for (int i = tid; i < 16 * WSP; i += 256) {   // shear p: Wsh[qi][t], kk = t+qi-15
      int qi = i / WSP, t = i - qi * WSP;
      int kk = t + qi - 15;
      Wsh[i] = (kk >= 0 && kk < 64) ? pbuf[qi * RPW + k0 + kk] : (unsigned short)0;
    }
    const int jb = k0 - q0 - 15;
    for (int i = tid; i < 64 * 96; i += 256) {    // rel_v^T window (clipped)
      int d = i / 96, t = i - d * 96;
      int pj = jb + t; pj = (pj < -512 ? -512 : (pj > 512 ? 512 : pj)) + 512;
      RVt[d * RVP + t] = rvT[d * 1040 + pj];
    }
    __syncthreads();
#pragma unroll
    for (int h = 0; h < 2; ++h) {
      s16x8 pa = *(const s16x8*)&pbuf[l15 * RPW + k0 + h * 32 + lhi * 8];
      s16x8 vf = *(const s16x8*)&Vt[(d0w + l15) * VTP + h * 32 + lhi * 8];
      acc = MFMA16(pa, vf, acc, 0, 0, 0);
    }
#pragma unroll
    for (int cc = 0; cc < 3; ++cc) {
      s16x8 wa = *(const s16x8*)&Wsh[l15 * WSP + cc * 32 + lhi * 8];
      s16x8 rb = *(const s16x8*)&RVt[(d0w + l15) * RVP + cc * 32 + lhi * 8];
      acc = MFMA16(wa, rb, acc, 0, 0, 0);
    }
  }
  // epilogue: scale by 1/Z, write bf16 to scrambled layout feeding the Wo GEMM
#pragma unroll
  for (int j = 0; j < 4; ++j) {
    int qi = lhi * 4 + j;
    float v = acc[j] * iz16[qi];
    size_t f = ((size_t)(bh >> 2) << 18) + ((size_t)(q0 + qi) << 8) + ((size_t)(bh & 3) << 6) + d0w + l15;
    xscr[f] = f2bf(v);
  }
}

extern "C" void kernel_launch(void* const* d_in, const int* in_sizes, int n_in,
                              void* d_out, int out_size, void* d_ws, size_t ws_size,
                              hipStream_t stream) {
  (void)in_sizes; (void)n_in; (void)out_size; (void)ws_size;
  const float* query = (const float*)d_in[0];
  const float* key   = (const float*)d_in[1];
  const float* value = (const float*)d_in[2];
  const float* Wq = (const float*)d_in[3];
  const float* bq = (const float*)d_in[4];
  const float* Wk = (const float*)d_in[5];
  const float* bk = (const float*)d_in[6];
  const float* Wv = (const float*)d_in[7];
  const float* bv = (const float*)d_in[8];
  const float* Wo = (const float*)d_in[9];
  const float* bo = (const float*)d_in[10];
  const float* rel_k = (const float*)d_in[11];
  const float* rel_v = (const float*)d_in[12];

  char* ws = (char*)d_ws;
  const size_t MB = 1024 * 1024;
  unsigned short* qb    = (unsigned short*)(ws);            //  8 MB [64][1024][64]
  unsigned short* kbuf  = (unsigned short*)(ws + 8 * MB);   //  8 MB
  unsigned short* vbuf  = (unsigned short*)(ws + 16 * MB);  //  8 MB
  unsigned short* tmp16 = (unsigned short*)(ws + 24 * MB);  //  8 MB (cvt input, later xscr)
  unsigned short* wt    = (unsigned short*)(ws + 32 * MB);  //  2 MB (current W^T)
  unsigned short* relkb = (unsigned short*)(ws + 34 * MB);  //  ~0.26 MB
  unsigned short* rvTb  = (unsigned short*)(ws + 35 * MB);  //  ~0.13 MB

  float* out0 = (float*)d_out;
  float* attn_out = out0 + 4194304;

  dim3 trb(32, 8), trg(32, 32);
  dim3 gg(8, 32);

  k_cvt_bf16<<<33, 256, 0, stream>>>(rel_k, relkb, 65600);
  k_relvT<<<257, 256, 0, stream>>>(rel_v, rvTb);

  k_cvt_bf16<<<2048, 256, 0, stream>>>(query, tmp16, 4194304);
  k_tr1024<<<trg, trb, 0, stream>>>(Wq, wt);
  k_gemm<0><<<gg, 256, 0, stream>>>(tmp16, wt, bq, qb);

  k_cvt_bf16<<<2048, 256, 0, stream>>>(key, tmp16, 4194304);
  k_tr1024<<<trg, trb, 0, stream>>>(Wk, wt);
  k_gemm<0><<<gg, 256, 0, stream>>>(tmp16, wt, bk, kbuf);

  k_cvt_bf16<<<2048, 256, 0, stream>>>(value, tmp16, 4194304);
  k_tr1024<<<trg, trb, 0, stream>>>(Wv, wt);
  k_gemm<0><<<gg, 256, 0, stream>>>(tmp16, wt, bv, vbuf);

  k_tr1024<<<trg, trb, 0, stream>>>(Wo, wt);

  // fused attention: attn (f32) to d_out; pre-scrambled X (bf16) into tmp16
  k_attn<<<4096, 256, 0, stream>>>(qb, kbuf, vbuf, relkb, rvTb, attn_out, tmp16);

  // output projection (f32 out)
  k_gemm<1><<<gg, 256, 0, stream>>>(tmp16, wt, bo, out0);
}

// Round 4
// 405.276 us; speedup vs baseline: 1.6544x; 1.6544x over previous
//
#include <hip/hip_runtime.h>

// B=4, S=1024, EMB=1024, H=16, HD=64, MAXP=512
// Outputs (float32, concatenated): out0 [4,1024,1024], attn [64,1024,1024]

using s16x8 = __attribute__((ext_vector_type(8))) short;
using f32x4 = __attribute__((ext_vector_type(4))) float;

#define MFMA16 __builtin_amdgcn_mfma_f32_16x16x32_bf16

__device__ __forceinline__ float bf2f(unsigned short u) {
  union { unsigned int u; float f; } v; v.u = ((unsigned int)u) << 16; return v.f;
}
__device__ __forceinline__ unsigned short f2bf(float f) {
  union { float f; unsigned int u; } v; v.f = f;
  unsigned int r = (v.u + 0x7FFFu + ((v.u >> 16) & 1u)) >> 16;
  return (unsigned short)r;
}

// ---------- fp32 -> bf16, 8 elems/thread ----------
__global__ void k_cvt_bf16(const float* __restrict__ in, unsigned short* __restrict__ out, int n) {
  int i = (blockIdx.x * 256 + threadIdx.x) * 8;
  if (i >= n) return;
  float4 a = *(const float4*)(in + i);
  float4 b = *(const float4*)(in + i + 4);
  s16x8 o;
  o[0] = (short)f2bf(a.x); o[1] = (short)f2bf(a.y); o[2] = (short)f2bf(a.z); o[3] = (short)f2bf(a.w);
  o[4] = (short)f2bf(b.x); o[5] = (short)f2bf(b.y); o[6] = (short)f2bf(b.z); o[7] = (short)f2bf(b.w);
  *(s16x8*)(out + i) = o;
}

// ---------- 1024x1024 transpose + cvt: Wt[n][k] = W[k][n] ----------
__global__ void k_tr1024(const float* __restrict__ W, unsigned short* __restrict__ Wt) {
  __shared__ float t[32][33];
  int tx = threadIdx.x, ty = threadIdx.y;           // 32 x 8
  int n0 = blockIdx.x * 32, k0 = blockIdx.y * 32;
#pragma unroll
  for (int r = 0; r < 4; ++r)
    t[ty * 4 + r][tx] = W[(size_t)(k0 + ty * 4 + r) * 1024 + n0 + tx];
  __syncthreads();
#pragma unroll
  for (int r = 0; r < 4; ++r)
    Wt[(size_t)(n0 + ty * 4 + r) * 1024 + k0 + tx] = f2bf(t[tx][ty * 4 + r]);
}

// ---------- rel tables prep: rel_k -> bf16 [1025][64]; rel_v -> rvT [64][1040] ----------
__global__ void k_relprep(const float* __restrict__ rk, const float* __restrict__ rv,
                          unsigned short* __restrict__ relkb, unsigned short* __restrict__ rvTb) {
  int b = blockIdx.x;
  if (b < 33) {
    int i = (b * 256 + threadIdx.x) * 8;
    if (i < 65600) {
      float4 a = *(const float4*)(rk + i);
      float4 c = *(const float4*)(rk + i + 4);
      s16x8 o;
      o[0] = (short)f2bf(a.x); o[1] = (short)f2bf(a.y); o[2] = (short)f2bf(a.z); o[3] = (short)f2bf(a.w);
      o[4] = (short)f2bf(c.x); o[5] = (short)f2bf(c.y); o[6] = (short)f2bf(c.z); o[7] = (short)f2bf(c.w);
      *(s16x8*)(relkb + i) = o;
    }
  } else {
    int i = (b - 33) * 256 + threadIdx.x;
    if (i < 65600) {
      int p = i >> 6, d = i & 63;
      rvTb[d * 1040 + p] = f2bf(rv[i]);
    }
  }
}

// ---------- per-head V transpose: vbuf [bh][s][d] -> vT [bh][d][s] ----------
__global__ __launch_bounds__(256)
void k_trV(const unsigned short* __restrict__ v, unsigned short* __restrict__ vt) {
  __shared__ unsigned short T[64][72];
  const int tid = threadIdx.x;
  const int bh = blockIdx.x >> 4;
  const int s0 = (blockIdx.x & 15) << 6;
  const int r = tid >> 2, cb = (tid & 3) << 4;
  const unsigned short* src = v + ((size_t)bh << 16) + (size_t)(s0 + r) * 64 + cb;
  *(s16x8*)&T[r][cb] = *(const s16x8*)src;
  *(s16x8*)&T[r][cb + 8] = *(const s16x8*)(src + 8);
  __syncthreads();
  unsigned short* dst = vt + ((size_t)bh << 16) + (size_t)r * 1024 + s0 + cb;
  s16x8 o0, o1;
#pragma unroll
  for (int e = 0; e < 8; ++e) o0[e] = T[cb + e][r];
#pragma unroll
  for (int e = 0; e < 8; ++e) o1[e] = T[cb + 8 + e][r];
  *(s16x8*)dst = o0;
  *(s16x8*)(dst + 8) = o1;
}

// ---------- bf16 GEMM: C[4096x1024] = A[4096x1024] @ BT[1024x1024]^T + bias ----------
// MODE 0: store bf16 to per-head layout [bh][s][d] ; MODE 1: store float32 row-major
template <int MODE>
__global__ __launch_bounds__(256, 2)
void k_gemm(const unsigned short* __restrict__ A, const unsigned short* __restrict__ BT,
            const float* __restrict__ bias, void* __restrict__ Cout) {
  __shared__ alignas(16) unsigned short aT[2][4096];
  __shared__ alignas(16) unsigned short bT[2][4096];
  const int tid = threadIdx.x;
  const int lane = tid & 63;
  const int l15 = lane & 15, lhi = lane >> 4;
  const int w = tid >> 6;
  const int wr = (w >> 1) * 64, wc = (w & 1) * 64;
  const int brow = blockIdx.y * 128, bcol = blockIdx.x * 128;
  f32x4 acc[4][4] = {};

#define STAGE(buf, kt) do {                                                              \
    int k0s = (kt) * 32;                                                                 \
    {                                                                                    \
      int c = tid;                                                                       \
      int row = c >> 2, k8 = (c & 3) * 8;                                                \
      __builtin_amdgcn_global_load_lds(                                                  \
        (const __attribute__((address_space(1))) void*)(A + (size_t)(brow + row) * 1024 + k0s + k8), \
        (__attribute__((address_space(3))) void*)(&aT[buf][c * 8]), 16, 0, 0);           \
      __builtin_amdgcn_global_load_lds(                                                  \
        (const __attribute__((address_space(1))) void*)(BT + (size_t)(bcol + row) * 1024 + k0s + k8),\
        (__attribute__((address_space(3))) void*)(&bT[buf][c * 8]), 16, 0, 0);           \
    }                                                                                    \
    {                                                                                    \
      int c = tid + 256;                                                                 \
      int row = c >> 2, k8 = (c & 3) * 8;                                                \
      __builtin_amdgcn_global_load_lds(                                                  \
        (const __attribute__((address_space(1))) void*)(A + (size_t)(brow + row) * 1024 + k0s + k8), \
        (__attribute__((address_space(3))) void*)(&aT[buf][c * 8]), 16, 0, 0);           \
      __builtin_amdgcn_global_load_lds(                                                  \
        (const __attribute__((address_space(1))) void*)(BT + (size_t)(bcol + row) * 1024 + k0s + k8),\
        (__attribute__((address_space(3))) void*)(&bT[buf][c * 8]), 16, 0, 0);           \
    }                                                                                    \
  } while (0)

  int cur = 0;
  STAGE(0, 0);
  for (int kt = 0; kt < 32; ++kt) {
    __syncthreads();
    if (kt + 1 < 32) STAGE(cur ^ 1, kt + 1);
    s16x8 af[4], bfv[4];
#pragma unroll
    for (int m = 0; m < 4; ++m)
      af[m] = *(const s16x8*)&aT[cur][(wr + m * 16 + l15) * 32 + lhi * 8];
#pragma unroll
    for (int n = 0; n < 4; ++n)
      bfv[n] = *(const s16x8*)&bT[cur][(wc + n * 16 + l15) * 32 + lhi * 8];
#pragma unroll
    for (int m = 0; m < 4; ++m)
#pragma unroll
      for (int n = 0; n < 4; ++n)
        acc[m][n] = MFMA16(af[m], bfv[n], acc[m][n], 0, 0, 0);
    __syncthreads();
    cur ^= 1;
  }
#undef STAGE

#pragma unroll
  for (int m = 0; m < 4; ++m) {
#pragma unroll
    for (int n = 0; n < 4; ++n) {
      int col = bcol + wc + n * 16 + l15;
      float bs = bias[col];
#pragma unroll
      for (int j = 0; j < 4; ++j) {
        int r = brow + wr + m * 16 + lhi * 4 + j;
        float v = acc[m][n][j] + bs;
        if (MODE == 0) {
          int b = r >> 10, s = r & 1023, h = col >> 6, d = col & 63;
          ((unsigned short*)Cout)[(((size_t)((b << 4) + h) * 1024 + s) << 6) + d] = f2bf(v);
        } else {
          ((float*)Cout)[(size_t)r * 1024 + col] = v;
        }
      }
    }
  }
}

// ---------- fused attention ----------
#define RPW 1032   // pbuf row stride (elems); 2064 B
#define PWP 520    // pw row stride (elems); 1040 B

__global__ __launch_bounds__(256, 3)
void k_attn(const unsigned short* __restrict__ qb, const unsigned short* __restrict__ kbm,
            const unsigned short* __restrict__ vT, const unsigned short* __restrict__ relk,
            const unsigned short* __restrict__ rvT, float* __restrict__ attn_out,
            unsigned short* __restrict__ xscr) {
  __shared__ alignas(16) unsigned short pbuf[16 * RPW];  // 33,024 B unnormalized exp
  __shared__ alignas(16) unsigned short pw[16 * PWP];    // 16,640 B sheared-p half
  __shared__ float red[3][4][16];
  __shared__ float izS[16], plS[16], phS[16];

  const int tid = threadIdx.x;
  const int lane = tid & 63;
  const int w = tid >> 6;
  const int l15 = lane & 15, lhi = lane >> 4;
  const int bh = blockIdx.x >> 6;
  const int q0 = (blockIdx.x & 63) << 4;

  const unsigned short* Qh = qb + ((size_t)bh << 16);
  const unsigned short* Kh = kbm + ((size_t)bh << 16);
  const unsigned short* Vth = vT + ((size_t)bh << 16);

  const unsigned short* qp = Qh + (size_t)(q0 + l15) * 64 + lhi * 8;
  s16x8 qa0 = *(const s16x8*)qp;
  s16x8 qa1 = *(const s16x8*)(qp + 32);

  // ---- single pass: e = exp((qk+rel)/8)  (no max-shift; logits/8 bounded ~8) ----
  float zp[4] = {0.f, 0.f, 0.f, 0.f};
  float lo[4] = {0.f, 0.f, 0.f, 0.f};
  float hi4[4] = {0.f, 0.f, 0.f, 0.f};
  for (int k0 = w * 16; k0 < 1024; k0 += 64) {
    const unsigned short* kp = Kh + (size_t)(k0 + l15) * 64 + lhi * 8;
    s16x8 kf0 = *(const s16x8*)kp;
    s16x8 kf1 = *(const s16x8*)(kp + 32);
    const int jb = k0 - q0 - 15;
    int p0 = jb + l15;      p0 = (p0 < -512 ? -512 : (p0 > 512 ? 512 : p0)) + 512;
    int p1 = jb + l15 + 16; p1 = (p1 < -512 ? -512 : (p1 > 512 ? 512 : p1)) + 512;
    const unsigned short* r0p = relk + (size_t)p0 * 64 + lhi * 8;
    const unsigned short* r1p = relk + (size_t)p1 * 64 + lhi * 8;
    s16x8 ra0 = *(const s16x8*)r0p, ra0h = *(const s16x8*)(r0p + 32);
    s16x8 ra1 = *(const s16x8*)r1p, ra1h = *(const s16x8*)(r1p + 32);
    f32x4 c = {0.f, 0.f, 0.f, 0.f};
    f32x4 w0 = {0.f, 0.f, 0.f, 0.f}, w1 = {0.f, 0.f, 0.f, 0.f};
    __builtin_amdgcn_s_setprio(1);
    c = MFMA16(qa0, kf0, c, 0, 0, 0);
    c = MFMA16(qa1, kf1, c, 0, 0, 0);
    w0 = MFMA16(qa0, ra0, w0, 0, 0, 0);  w0 = MFMA16(qa1, ra0h, w0, 0, 0, 0);
    w1 = MFMA16(qa0, ra1, w1, 0, 0, 0);  w1 = MFMA16(qa1, ra1h, w1, 0, 0, 0);
    __builtin_amdgcn_s_setprio(0);
#pragma unroll
    for (int j = 0; j < 4; ++j) {
      int qi = lhi * 4 + j;
      int ts = l15 - qi + 15;                 // [0,30]
      int sl = (lane & 48) | (ts & 15);
      float a0 = __shfl(w0[j], sl, 64);
      float a1 = __shfl(w1[j], sl, 64);
      float rel = (ts & 16) ? a1 : a0;
      float e = __expf((c[j] + rel) * 0.125f);
      zp[j] += e;
      int dd = k0 + l15 - q0 - qi;
      lo[j]  += (dd <= -512) ? e : 0.f;
      hi4[j] += (dd >=  512) ? e : 0.f;
      pbuf[qi * RPW + k0 + l15] = f2bf(e);
    }
  }
#pragma unroll
  for (int off = 1; off < 16; off <<= 1)
#pragma unroll
    for (int j = 0; j < 4; ++j) {
      zp[j]  += __shfl_xor(zp[j], off, 64);
      lo[j]  += __shfl_xor(lo[j], off, 64);
      hi4[j] += __shfl_xor(hi4[j], off, 64);
    }
  if (l15 == 0) {
#pragma unroll
    for (int j = 0; j < 4; ++j) {
      red[0][w][lhi * 4 + j] = zp[j];
      red[1][w][lhi * 4 + j] = lo[j];
      red[2][w][lhi * 4 + j] = hi4[j];
    }
  }
  __syncthreads();
  if (tid < 16) {
    izS[tid] = 1.0f / (red[0][0][tid] + red[0][1][tid] + red[0][2][tid] + red[0][3][tid]);
    plS[tid] = red[1][0][tid] + red[1][1][tid] + red[1][2][tid] + red[1][3][tid];
    phS[tid] = red[2][0][tid] + red[2][1][tid] + red[2][2][tid] + red[2][3][tid];
  }
  __syncthreads();

  // ---- normalized attn -> d_out (f32, vectorized, nontemporal) ----
  {
    float* ao = attn_out + ((size_t)bh << 20) + ((size_t)q0 << 10);
#pragma unroll
    for (int n = 0; n < 8; ++n) {
      int e8 = tid * 8 + n * 2048;
      int r = e8 >> 10, cc = e8 & 1023;
      float iz = izS[r];
      s16x8 p8 = *(const s16x8*)&pbuf[r * RPW + cc];
      f32x4 o0, o1;
      o0[0] = bf2f((unsigned short)p8[0]) * iz; o0[1] = bf2f((unsigned short)p8[1]) * iz;
      o0[2] = bf2f((unsigned short)p8[2]) * iz; o0[3] = bf2f((unsigned short)p8[3]) * iz;
      o1[0] = bf2f((unsigned short)p8[4]) * iz; o1[1] = bf2f((unsigned short)p8[5]) * iz;
      o1[2] = bf2f((unsigned short)p8[6]) * iz; o1[3] = bf2f((unsigned short)p8[7]) * iz;
      __builtin_nontemporal_store(o0, (f32x4*)(ao + e8));
      __builtin_nontemporal_store(o1, (f32x4*)(ao + e8 + 4));
    }
  }

  // ---- PV: acc[q][d] += p . V  (V^T direct from global/L2, no LDS, no syncs) ----
  f32x4 acc = {0.f, 0.f, 0.f, 0.f};
  const int d0w = w << 4;
  const unsigned short* vrow = Vth + (size_t)(d0w + l15) * 1024 + lhi * 8;
#pragma unroll 8
  for (int kc = 0; kc < 1024; kc += 32) {
    s16x8 pa = *(const s16x8*)&pbuf[l15 * RPW + kc + lhi * 8];
    s16x8 vf = *(const s16x8*)(vrow + kc);
    acc = MFMA16(pa, vf, acc, 0, 0, 0);
  }

  // ---- rel_v GEMM over globally-sheared p (two 512-halves) ----
  const unsigned short* rrow = rvT + (size_t)(d0w + l15) * 1040 + lhi * 8;
  for (int ph = 0; ph < 2; ++ph) {
    __syncthreads();
    for (int n = 0; n < 32; ++n) {
      int e = n * 256 + tid;
      int qi = e >> 9, pp = e & 511;
      int p = (ph << 9) | pp;
      int k = q0 + qi + p - 512;
      unsigned short val;
      if (p == 0) val = f2bf(plS[qi]);
      else val = (k >= 0 && k < 1024) ? pbuf[qi * RPW + k] : (unsigned short)0;
      pw[qi * PWP + pp] = val;
    }
    __syncthreads();
#pragma unroll 8
    for (int kc = 0; kc < 512; kc += 32) {
      s16x8 pa = *(const s16x8*)&pw[l15 * PWP + kc + lhi * 8];
      s16x8 rb = *(const s16x8*)(rrow + (ph << 9) + kc);
      acc = MFMA16(pa, rb, acc, 0, 0, 0);
    }
  }

  // ---- epilogue: + phigh * rel_v[1024], scale by iz, scrambled bf16 store ----
  float rv1024 = bf2f(rvT[(size_t)(d0w + l15) * 1040 + 1024]);
  const size_t fb = ((size_t)(bh >> 2) << 18) + ((size_t)(bh & 3) << 6);
#pragma unroll
  for (int j = 0; j < 4; ++j) {
    int qi = lhi * 4 + j;
    float v = (acc[j] + phS[qi] * rv1024) * izS[qi];
    xscr[fb + ((size_t)(q0 + qi) << 8) + d0w + l15] = f2bf(v);
  }
}

extern "C" void kernel_launch(void* const* d_in, const int* in_sizes, int n_in,
                              void* d_out, int out_size, void* d_ws, size_t ws_size,
                              hipStream_t stream) {
  (void)in_sizes; (void)n_in; (void)out_size; (void)ws_size;
  const float* query = (const float*)d_in[0];
  const float* key   = (const float*)d_in[1];
  const float* value = (const float*)d_in[2];
  const float* Wq = (const float*)d_in[3];
  const float* bq = (const float*)d_in[4];
  const float* Wk = (const float*)d_in[5];
  const float* bk = (const float*)d_in[6];
  const float* Wv = (const float*)d_in[7];
  const float* bv = (const float*)d_in[8];
  const float* Wo = (const float*)d_in[9];
  const float* bo = (const float*)d_in[10];
  const float* rel_k = (const float*)d_in[11];
  const float* rel_v = (const float*)d_in[12];

  char* ws = (char*)d_ws;
  const size_t MB = 1024 * 1024;
  unsigned short* qb    = (unsigned short*)(ws);            //  8 MB [64][1024][64]
  unsigned short* kbuf  = (unsigned short*)(ws + 8 * MB);   //  8 MB
  unsigned short* vbuf  = (unsigned short*)(ws + 16 * MB);  //  8 MB (dead after k_trV -> xscr)
  unsigned short* tmp16 = (unsigned short*)(ws + 24 * MB);  //  8 MB (cvt input; dead after V-GEMM -> vT)
  unsigned short* wt    = (unsigned short*)(ws + 32 * MB);  //  2 MB (current W^T)
  unsigned short* relkb = (unsigned short*)(ws + 34 * MB);  //  ~0.13 MB
  unsigned short* rvTb  = (unsigned short*)(ws + 34 * MB + 512 * 1024);  // ~0.13 MB
  unsigned short* vTb   = tmp16;                            // reuse
  unsigned short* xscr  = vbuf;                             // reuse

  float* out0 = (float*)d_out;
  float* attn_out = out0 + 4194304;

  dim3 trb(32, 8), trg(32, 32);
  dim3 gg(8, 32);

  k_relprep<<<290, 256, 0, stream>>>(rel_k, rel_v, relkb, rvTb);

  k_cvt_bf16<<<2048, 256, 0, stream>>>(query, tmp16, 4194304);
  k_tr1024<<<trg, trb, 0, stream>>>(Wq, wt);
  k_gemm<0><<<gg, 256, 0, stream>>>(tmp16, wt, bq, qb);

  k_cvt_bf16<<<2048, 256, 0, stream>>>(key, tmp16, 4194304);
  k_tr1024<<<trg, trb, 0, stream>>>(Wk, wt);
  k_gemm<0><<<gg, 256, 0, stream>>>(tmp16, wt, bk, kbuf);

  k_cvt_bf16<<<2048, 256, 0, stream>>>(value, tmp16, 4194304);
  k_tr1024<<<trg, trb, 0, stream>>>(Wv, wt);
  k_gemm<0><<<gg, 256, 0, stream>>>(tmp16, wt, bv, vbuf);

  k_trV<<<1024, 256, 0, stream>>>(vbuf, vTb);       // vbuf -> vT (tmp16 region)
  k_tr1024<<<trg, trb, 0, stream>>>(Wo, wt);

  // fused attention: attn (f32) -> d_out; pre-scrambled X (bf16) -> xscr (vbuf region)
  k_attn<<<4096, 256, 0, stream>>>(qb, kbuf, vTb, relkb, rvTb, attn_out, xscr);

  // output projection (f32 out)
  k_gemm<1><<<gg, 256, 0, stream>>>(xscr, wt, bo, out0);
}

// Round 5
// 395.830 us; speedup vs baseline: 1.6939x; 1.0239x over previous
//
#include <hip/hip_runtime.h>

// B=4, S=1024, EMB=1024, H=16, HD=64, MAXP=512
// Outputs (float32, concatenated): out0 [4,1024,1024], attn [64,1024,1024]

using s16x8 = __attribute__((ext_vector_type(8))) short;
using f32x4 = __attribute__((ext_vector_type(4))) float;

#define MFMA16 __builtin_amdgcn_mfma_f32_16x16x32_bf16

__device__ __forceinline__ float bf2f(unsigned short u) {
  union { unsigned int u; float f; } v; v.u = ((unsigned int)u) << 16; return v.f;
}
__device__ __forceinline__ unsigned short f2bf(float f) {
  union { float f; unsigned int u; } v; v.f = f;
  unsigned int r = (v.u + 0x7FFFu + ((v.u >> 16) & 1u)) >> 16;
  return (unsigned short)r;
}

// ---------- fp32 -> bf16, 8 elems/thread ----------
__global__ void k_cvt_bf16(const float* __restrict__ in, unsigned short* __restrict__ out, int n) {
  int i = (blockIdx.x * 256 + threadIdx.x) * 8;
  if (i >= n) return;
  float4 a = *(const float4*)(in + i);
  float4 b = *(const float4*)(in + i + 4);
  s16x8 o;
  o[0] = (short)f2bf(a.x); o[1] = (short)f2bf(a.y); o[2] = (short)f2bf(a.z); o[3] = (short)f2bf(a.w);
  o[4] = (short)f2bf(b.x); o[5] = (short)f2bf(b.y); o[6] = (short)f2bf(b.z); o[7] = (short)f2bf(b.w);
  *(s16x8*)(out + i) = o;
}

// ---------- 1024x1024 transpose + cvt: Wt[n][k] = W[k][n] ----------
__global__ void k_tr1024(const float* __restrict__ W, unsigned short* __restrict__ Wt) {
  __shared__ float t[32][33];
  int tx = threadIdx.x, ty = threadIdx.y;           // 32 x 8
  int n0 = blockIdx.x * 32, k0 = blockIdx.y * 32;
#pragma unroll
  for (int r = 0; r < 4; ++r)
    t[ty * 4 + r][tx] = W[(size_t)(k0 + ty * 4 + r) * 1024 + n0 + tx];
  __syncthreads();
#pragma unroll
  for (int r = 0; r < 4; ++r)
    Wt[(size_t)(n0 + ty * 4 + r) * 1024 + k0 + tx] = f2bf(t[tx][ty * 4 + r]);
}

// ---------- rel tables prep: rel_k -> bf16 [1025][64]; rel_v -> rvT [64][1040] ----------
__global__ void k_relprep(const float* __restrict__ rk, const float* __restrict__ rv,
                          unsigned short* __restrict__ relkb, unsigned short* __restrict__ rvTb) {
  int b = blockIdx.x;
  if (b < 33) {
    int i = (b * 256 + threadIdx.x) * 8;
    if (i < 65600) {
      float4 a = *(const float4*)(rk + i);
      float4 c = *(const float4*)(rk + i + 4);
      s16x8 o;
      o[0] = (short)f2bf(a.x); o[1] = (short)f2bf(a.y); o[2] = (short)f2bf(a.z); o[3] = (short)f2bf(a.w);
      o[4] = (short)f2bf(c.x); o[5] = (short)f2bf(c.y); o[6] = (short)f2bf(c.z); o[7] = (short)f2bf(c.w);
      *(s16x8*)(relkb + i) = o;
    }
  } else {
    int i = (b - 33) * 256 + threadIdx.x;
    if (i < 65600) {
      int p = i >> 6, d = i & 63;
      rvTb[d * 1040 + p] = f2bf(rv[i]);
    }
  }
}

// ---------- per-head V transpose: vbuf [bh][s][d] -> vT [bh][d][s] ----------
__global__ __launch_bounds__(256)
void k_trV(const unsigned short* __restrict__ v, unsigned short* __restrict__ vt) {
  __shared__ unsigned short T[64][72];
  const int tid = threadIdx.x;
  const int bh = blockIdx.x >> 4;
  const int s0 = (blockIdx.x & 15) << 6;
  const int r = tid >> 2, cb = (tid & 3) << 4;
  const unsigned short* src = v + ((size_t)bh << 16) + (size_t)(s0 + r) * 64 + cb;
  *(s16x8*)&T[r][cb] = *(const s16x8*)src;
  *(s16x8*)&T[r][cb + 8] = *(const s16x8*)(src + 8);
  __syncthreads();
  unsigned short* dst = vt + ((size_t)bh << 16) + (size_t)r * 1024 + s0 + cb;
  s16x8 o0, o1;
#pragma unroll
  for (int e = 0; e < 8; ++e) o0[e] = T[cb + e][r];
#pragma unroll
  for (int e = 0; e < 8; ++e) o1[e] = T[cb + 8 + e][r];
  *(s16x8*)dst = o0;
  *(s16x8*)(dst + 8) = o1;
}

// ---------- bf16 GEMM: C[4096x1024] = A[4096x1024] @ BT[1024x1024]^T + bias ----------
// tile 128x64, grid (16,32) = 512 blocks (2/CU).
// MODE 0: store bf16 to per-head layout [bh][s][d] ; MODE 1: store float32 row-major
template <int MODE>
__global__ __launch_bounds__(256, 2)
void k_gemm(const unsigned short* __restrict__ A, const unsigned short* __restrict__ BT,
            const float* __restrict__ bias, void* __restrict__ Cout) {
  __shared__ alignas(16) unsigned short aT[2][4096];
  __shared__ alignas(16) unsigned short bT[2][2048];
  const int tid = threadIdx.x;
  const int lane = tid & 63;
  const int l15 = lane & 15, lhi = lane >> 4;
  const int w = tid >> 6;
  const int wr = w * 32;
  const int brow = blockIdx.y * 128, bcol = blockIdx.x * 64;
  f32x4 acc[2][4] = {};

#define STAGE(buf, kt) do {                                                              \
    int k0s = (kt) * 32;                                                                 \
    {                                                                                    \
      int c = tid;                                                                       \
      int row = c >> 2, k8 = (c & 3) * 8;                                                \
      __builtin_amdgcn_global_load_lds(                                                  \
        (const __attribute__((address_space(1))) void*)(A + (size_t)(brow + row) * 1024 + k0s + k8), \
        (__attribute__((address_space(3))) void*)(&aT[buf][c * 8]), 16, 0, 0);           \
      __builtin_amdgcn_global_load_lds(                                                  \
        (const __attribute__((address_space(1))) void*)(BT + (size_t)(bcol + row) * 1024 + k0s + k8),\
        (__attribute__((address_space(3))) void*)(&bT[buf][c * 8]), 16, 0, 0);           \
    }                                                                                    \
    {                                                                                    \
      int c = tid + 256;                                                                 \
      int row = c >> 2, k8 = (c & 3) * 8;                                                \
      __builtin_amdgcn_global_load_lds(                                                  \
        (const __attribute__((address_space(1))) void*)(A + (size_t)(brow + row) * 1024 + k0s + k8), \
        (__attribute__((address_space(3))) void*)(&aT[buf][c * 8]), 16, 0, 0);           \
    }                                                                                    \
  } while (0)

  int cur = 0;
  STAGE(0, 0);
  for (int kt = 0; kt < 32; ++kt) {
    __syncthreads();
    if (kt + 1 < 32) STAGE(cur ^ 1, kt + 1);
    s16x8 af[2], bfv[4];
#pragma unroll
    for (int m = 0; m < 2; ++m)
      af[m] = *(const s16x8*)&aT[cur][(wr + m * 16 + l15) * 32 + lhi * 8];
#pragma unroll
    for (int n = 0; n < 4; ++n)
      bfv[n] = *(const s16x8*)&bT[cur][(n * 16 + l15) * 32 + lhi * 8];
#pragma unroll
    for (int m = 0; m < 2; ++m)
#pragma unroll
      for (int n = 0; n < 4; ++n)
        acc[m][n] = MFMA16(af[m], bfv[n], acc[m][n], 0, 0, 0);
    __syncthreads();
    cur ^= 1;
  }
#undef STAGE

#pragma unroll
  for (int m = 0; m < 2; ++m) {
#pragma unroll
    for (int n = 0; n < 4; ++n) {
      int col = bcol + n * 16 + l15;
      float bs = bias[col];
#pragma unroll
      for (int j = 0; j < 4; ++j) {
        int r = brow + wr + m * 16 + lhi * 4 + j;
        float v = acc[m][n][j] + bs;
        if (MODE == 0) {
          int b = r >> 10, s = r & 1023, h = col >> 6, d = col & 63;
          ((unsigned short*)Cout)[(((size_t)((b << 4) + h) * 1024 + s) << 6) + d] = f2bf(v);
        } else {
          ((float*)Cout)[(size_t)r * 1024 + col] = v;
        }
      }
    }
  }
}

// ---------- fused attention ----------
#define RPW 1032   // pbuf row stride (elems); 2064 B
#define PWP 520    // pw row stride (elems); 1040 B

__global__ __launch_bounds__(256, 3)
void k_attn(const unsigned short* __restrict__ qb, const unsigned short* __restrict__ kbm,
            const unsigned short* __restrict__ vT, const unsigned short* __restrict__ relk,
            const unsigned short* __restrict__ rvT, float* __restrict__ attn_out,
            unsigned short* __restrict__ xscr) {
  __shared__ alignas(16) unsigned short pbuf[16 * RPW];  // 33,024 B unnormalized exp
  __shared__ alignas(16) unsigned short pw[16 * PWP];    // 16,640 B sheared-p half
  __shared__ float red[4][16];
  __shared__ float izS[16], plS[16], phS[16];

  const int tid = threadIdx.x;
  const int lane = tid & 63;
  const int w = tid >> 6;
  const int l15 = lane & 15, lhi = lane >> 4;
  // XCD-aware swizzle: XCD x (dispatch round-robin bid%8) owns heads [x*8, x*8+8)
  const int orig = ((blockIdx.x & 7) << 9) | (blockIdx.x >> 3);
  const int bh = orig >> 6;
  const int q0 = (orig & 63) << 4;

  const unsigned short* Qh = qb + ((size_t)bh << 16);
  const unsigned short* Kh = kbm + ((size_t)bh << 16);
  const unsigned short* Vth = vT + ((size_t)bh << 16);

  const unsigned short* qp = Qh + (size_t)(q0 + l15) * 64 + lhi * 8;
  s16x8 qa0 = *(const s16x8*)qp;
  s16x8 qa1 = *(const s16x8*)(qp + 32);

  // ---- single pass: e = exp((qk+rel)/8) -> pbuf; Z accumulated in-loop ----
  float zp[4] = {0.f, 0.f, 0.f, 0.f};
  for (int k0 = w * 16; k0 < 1024; k0 += 64) {
    const unsigned short* kp = Kh + (size_t)(k0 + l15) * 64 + lhi * 8;
    s16x8 kf0 = *(const s16x8*)kp;
    s16x8 kf1 = *(const s16x8*)(kp + 32);
    const int jb = k0 - q0 - 15;
    int p0 = jb + l15;      p0 = (p0 < -512 ? -512 : (p0 > 512 ? 512 : p0)) + 512;
    int p1 = jb + l15 + 16; p1 = (p1 < -512 ? -512 : (p1 > 512 ? 512 : p1)) + 512;
    const unsigned short* r0p = relk + (size_t)p0 * 64 + lhi * 8;
    const unsigned short* r1p = relk + (size_t)p1 * 64 + lhi * 8;
    s16x8 ra0 = *(const s16x8*)r0p, ra0h = *(const s16x8*)(r0p + 32);
    s16x8 ra1 = *(const s16x8*)r1p, ra1h = *(const s16x8*)(r1p + 32);
    f32x4 c = {0.f, 0.f, 0.f, 0.f};
    f32x4 w0 = {0.f, 0.f, 0.f, 0.f}, w1 = {0.f, 0.f, 0.f, 0.f};
    __builtin_amdgcn_s_setprio(1);
    c = MFMA16(qa0, kf0, c, 0, 0, 0);
    c = MFMA16(qa1, kf1, c, 0, 0, 0);
    w0 = MFMA16(qa0, ra0, w0, 0, 0, 0);  w0 = MFMA16(qa1, ra0h, w0, 0, 0, 0);
    w1 = MFMA16(qa0, ra1, w1, 0, 0, 0);  w1 = MFMA16(qa1, ra1h, w1, 0, 0, 0);
    __builtin_amdgcn_s_setprio(0);
#pragma unroll
    for (int j = 0; j < 4; ++j) {
      int qi = lhi * 4 + j;
      int ts = l15 - qi + 15;                 // [0,30]
      int sl = (lane & 48) | (ts & 15);
      float a0 = __shfl(w0[j], sl, 64);
      float a1 = __shfl(w1[j], sl, 64);
      float rel = (ts & 16) ? a1 : a0;
      float e = __expf((c[j] + rel) * 0.125f);
      zp[j] += e;
      pbuf[qi * RPW + k0 + l15] = f2bf(e);
    }
  }
#pragma unroll
  for (int off = 1; off < 16; off <<= 1)
#pragma unroll
    for (int j = 0; j < 4; ++j) zp[j] += __shfl_xor(zp[j], off, 64);
  if (l15 == 0) {
#pragma unroll
    for (int j = 0; j < 4; ++j) red[w][lhi * 4 + j] = zp[j];
  }
  __syncthreads();   // pbuf + red complete
  if (tid < 16)
    izS[tid] = 1.0f / (red[0][tid] + red[1][tid] + red[2][tid] + red[3][tid]);

  // ---- clip-mass post-pass: plS (k <= qa-512) or phS (k >= qa+512), one region/row ----
  {
    const int qi = tid >> 4, tq = tid & 15;
    const int qa = q0 + qi;
    int lo, hi;
    const bool isPh = (qa < 512);
    if (isPh) { lo = qa + 512; hi = 1024; }
    else      { lo = 0;        hi = qa - 511; }
    float s = 0.f;
    const unsigned short* srow = pbuf + qi * RPW;
    const int kb0 = lo & ~7;
    for (int k8 = kb0 + tq * 8; k8 < hi; k8 += 128) {
      s16x8 v8 = *(const s16x8*)&srow[k8];
#pragma unroll
      for (int e = 0; e < 8; ++e) {
        int k = k8 + e;
        s += (k >= lo && k < hi) ? bf2f((unsigned short)v8[e]) : 0.f;
      }
    }
#pragma unroll
    for (int off = 1; off < 16; off <<= 1) s += __shfl_xor(s, off, 64);
    if (tq == 0) { plS[qi] = isPh ? 0.f : s; phS[qi] = isPh ? s : 0.f; }
  }
  __syncthreads();   // izS, plS, phS ready

  // ---- normalized attn -> d_out (f32, 1KB-contiguous per wave-instr, NT) ----
  {
    float* ao = attn_out + ((size_t)bh << 20) + ((size_t)q0 << 10);
#pragma unroll
    for (int n = 0; n < 16; ++n) {
      float iz = izS[n];
      union { unsigned int u[2]; } pv;
      *(uint2*)pv.u = *(const uint2*)&pbuf[n * RPW + tid * 4];
      union { unsigned int u; float f; } b0, b1, b2, b3;
      b0.u = pv.u[0] << 16; b1.u = pv.u[0] & 0xFFFF0000u;
      b2.u = pv.u[1] << 16; b3.u = pv.u[1] & 0xFFFF0000u;
      f32x4 o;
      o[0] = b0.f * iz; o[1] = b1.f * iz; o[2] = b2.f * iz; o[3] = b3.f * iz;
      __builtin_nontemporal_store(o, (f32x4*)(ao + (n << 10) + tid * 4));
    }
  }

  // ---- PV: acc[q][d] += p . V  (V^T from global/L2, no LDS, no syncs) ----
  f32x4 acc = {0.f, 0.f, 0.f, 0.f};
  const int d0w = w << 4;
  const unsigned short* vrow = Vth + (size_t)(d0w + l15) * 1024 + lhi * 8;
#pragma unroll 8
  for (int kc = 0; kc < 1024; kc += 32) {
    s16x8 pa = *(const s16x8*)&pbuf[l15 * RPW + kc + lhi * 8];
    s16x8 vf = *(const s16x8*)(vrow + kc);
    acc = MFMA16(pa, vf, acc, 0, 0, 0);
  }

  // ---- rel_v GEMM over globally-sheared p (two 512-halves, vector-shift staging) ----
  const unsigned short* rrow = rvT + (size_t)(d0w + l15) * 1040 + lhi * 8;
  {
    const int sqi = tid >> 4, stq = tid & 15;
    const int ssh = sqi & 7, shs = ssh >> 1;
    const bool sodd = (ssh & 1) != 0;
    unsigned short* drow = pw + sqi * PWP;
    const unsigned short* srow = pbuf + sqi * RPW;
    for (int ph = 0; ph < 2; ++ph) {
      __syncthreads();
      const int base = q0 + sqi + (ph ? 0 : -512);
      for (int t = stq; t < 64; t += 16) {
        const int kw0 = base + t * 8;
        s16x8 o;
        if (kw0 >= 0 && kw0 + 8 <= 1024) {
          // all-in: two aligned b128 reads + funnel shift by ssh halfwords
          const int A = kw0 - ssh;            // multiple of 8, >= 0
          union { s16x8 v; unsigned int u[4]; } a0, a1, ov;
          a0.v = *(const s16x8*)&srow[A];
          a1.v = *(const s16x8*)&srow[A + 8];
          unsigned int wd[8];
#pragma unroll
          for (int j2 = 0; j2 < 4; ++j2) { wd[j2] = a0.u[j2]; wd[4 + j2] = a1.u[j2]; }
          unsigned int v7[7];
#pragma unroll
          for (int j2 = 0; j2 < 7; ++j2) {
            unsigned int sf = (wd[j2] >> 16) | (wd[j2 + 1] << 16);
            v7[j2] = sodd ? sf : wd[j2];
          }
#pragma unroll
          for (int j2 = 0; j2 < 4; ++j2) {
            unsigned int t0 = (shs & 1) ? v7[j2 + 1] : v7[j2];
            unsigned int t1 = (shs & 1) ? v7[j2 + 3] : v7[j2 + 2];
            ov.u[j2] = (shs & 2) ? t1 : t0;
          }
          o = ov.v;
        } else if (kw0 + 8 <= 0 || kw0 >= 1024) {
          o = (s16x8){0, 0, 0, 0, 0, 0, 0, 0};
        } else {
          // straddle (<=1 chunk per row per boundary): elementwise guarded
#pragma unroll
          for (int e = 0; e < 8; ++e) {
            int k = kw0 + e;
            int kc2 = k < 0 ? 0 : (k > 1023 ? 1023 : k);
            unsigned short vv = srow[kc2];
            o[e] = (k >= 0 && k < 1024) ? (short)vv : (short)0;
          }
        }
        *(s16x8*)&drow[t * 8] = o;
        if (ph == 0 && t == 0) drow[0] = f2bf(plS[sqi]);  // p=0 carries clip-low mass
      }
      __syncthreads();
#pragma unroll 8
      for (int kc = 0; kc < 512; kc += 32) {
        s16x8 pa = *(const s16x8*)&pw[l15 * PWP + kc + lhi * 8];
        s16x8 rb = *(const s16x8*)(rrow + (ph << 9) + kc);
        acc = MFMA16(pa, rb, acc, 0, 0, 0);
      }
    }
  }

  // ---- epilogue: + phigh * rel_v[1024], scale by iz, scrambled bf16 store ----
  float rv1024 = bf2f(rvT[(size_t)(d0w + l15) * 1040 + 1024]);
  const size_t fb = ((size_t)(bh >> 2) << 18) + ((size_t)(bh & 3) << 6);
#pragma unroll
  for (int j = 0; j < 4; ++j) {
    int qi = lhi * 4 + j;
    float v = (acc[j] + phS[qi] * rv1024) * izS[qi];
    xscr[fb + ((size_t)(q0 + qi) << 8) + d0w + l15] = f2bf(v);
  }
}

extern "C" void kernel_launch(void* const* d_in, const int* in_sizes, int n_in,
                              void* d_out, int out_size, void* d_ws, size_t ws_size,
                              hipStream_t stream) {
  (void)in_sizes; (void)n_in; (void)out_size; (void)ws_size;
  const float* query = (const float*)d_in[0];
  const float* key   = (const float*)d_in[1];
  const float* value = (const float*)d_in[2];
  const float* Wq = (const float*)d_in[3];
  const float* bq = (const float*)d_in[4];
  const float* Wk = (const float*)d_in[5];
  const float* bk = (const float*)d_in[6];
  const float* Wv = (const float*)d_in[7];
  const float* bv = (const float*)d_in[8];
  const float* Wo = (const float*)d_in[9];
  const float* bo = (const float*)d_in[10];
  const float* rel_k = (const float*)d_in[11];
  const float* rel_v = (const float*)d_in[12];

  char* ws = (char*)d_ws;
  const size_t MB = 1024 * 1024;
  unsigned short* qb    = (unsigned short*)(ws);            //  8 MB [64][1024][64]
  unsigned short* kbuf  = (unsigned short*)(ws + 8 * MB);   //  8 MB
  unsigned short* vbuf  = (unsigned short*)(ws + 16 * MB);  //  8 MB (dead after k_trV -> xscr)
  unsigned short* tmp16 = (unsigned short*)(ws + 24 * MB);  //  8 MB (cvt input; later vT)
  unsigned short* wt    = (unsigned short*)(ws + 32 * MB);  //  2 MB (current W^T)
  unsigned short* relkb = (unsigned short*)(ws + 34 * MB);  //  ~0.13 MB
  unsigned short* rvTb  = (unsigned short*)(ws + 34 * MB + 512 * 1024);  // ~0.13 MB
  unsigned short* vTb   = tmp16;                            // reuse
  unsigned short* xscr  = vbuf;                             // reuse

  float* out0 = (float*)d_out;
  float* attn_out = out0 + 4194304;

  dim3 trb(32, 8), trg(32, 32);
  dim3 gg(16, 32);

  k_relprep<<<290, 256, 0, stream>>>(rel_k, rel_v, relkb, rvTb);

  k_cvt_bf16<<<2048, 256, 0, stream>>>(query, tmp16, 4194304);
  k_tr1024<<<trg, trb, 0, stream>>>(Wq, wt);
  k_gemm<0><<<gg, 256, 0, stream>>>(tmp16, wt, bq, qb);

  k_cvt_bf16<<<2048, 256, 0, stream>>>(key, tmp16, 4194304);
  k_tr1024<<<trg, trb, 0, stream>>>(Wk, wt);
  k_gemm<0><<<gg, 256, 0, stream>>>(tmp16, wt, bk, kbuf);

  k_cvt_bf16<<<2048, 256, 0, stream>>>(value, tmp16, 4194304);
  k_tr1024<<<trg, trb, 0, stream>>>(Wv, wt);
  k_gemm<0><<<gg, 256, 0, stream>>>(tmp16, wt, bv, vbuf);

  k_trV<<<1024, 256, 0, stream>>>(vbuf, vTb);       // vbuf -> vT (tmp16 region)
  k_tr1024<<<trg, trb, 0, stream>>>(Wo, wt);

  // fused attention: attn (f32) -> d_out; pre-scrambled X (bf16) -> xscr (vbuf region)
  k_attn<<<4096, 256, 0, stream>>>(qb, kbuf, vTb, relkb, rvTb, attn_out, xscr);

  // output projection (f32 out)
  k_gemm<1><<<gg, 256, 0, stream>>>(xscr, wt, bo, out0);
}

// Round 6
// 368.631 us; speedup vs baseline: 1.8189x; 1.0738x over previous
//
#include <hip/hip_runtime.h>

// B=4, S=1024, EMB=1024, H=16, HD=64, MAXP=512
// Outputs (float32, concatenated): out0 [4,1024,1024], attn [64,1024,1024]

using s16x8 = __attribute__((ext_vector_type(8))) short;
using f32x4 = __attribute__((ext_vector_type(4))) float;

#define MFMA16 __builtin_amdgcn_mfma_f32_16x16x32_bf16

__device__ __forceinline__ float bf2f(unsigned short u) {
  union { unsigned int u; float f; } v; v.u = ((unsigned int)u) << 16; return v.f;
}
__device__ __forceinline__ unsigned short f2bf(float f) {
  union { float f; unsigned int u; } v; v.f = f;
  unsigned int r = (v.u + 0x7FFFu + ((v.u >> 16) & 1u)) >> 16;
  return (unsigned short)r;
}

// ---------- fp32 -> bf16, 8 elems/thread ----------
__global__ void k_cvt_bf16(const float* __restrict__ in, unsigned short* __restrict__ out, int n) {
  int i = (blockIdx.x * 256 + threadIdx.x) * 8;
  if (i >= n) return;
  float4 a = *(const float4*)(in + i);
  float4 b = *(const float4*)(in + i + 4);
  s16x8 o;
  o[0] = (short)f2bf(a.x); o[1] = (short)f2bf(a.y); o[2] = (short)f2bf(a.z); o[3] = (short)f2bf(a.w);
  o[4] = (short)f2bf(b.x); o[5] = (short)f2bf(b.y); o[6] = (short)f2bf(b.z); o[7] = (short)f2bf(b.w);
  *(s16x8*)(out + i) = o;
}

// ---------- 1024x1024 transpose + cvt: Wt[n][k] = W[k][n] ----------
__global__ void k_tr1024(const float* __restrict__ W, unsigned short* __restrict__ Wt) {
  __shared__ float t[32][33];
  int tx = threadIdx.x, ty = threadIdx.y;           // 32 x 8
  int n0 = blockIdx.x * 32, k0 = blockIdx.y * 32;
#pragma unroll
  for (int r = 0; r < 4; ++r)
    t[ty * 4 + r][tx] = W[(size_t)(k0 + ty * 4 + r) * 1024 + n0 + tx];
  __syncthreads();
#pragma unroll
  for (int r = 0; r < 4; ++r)
    Wt[(size_t)(n0 + ty * 4 + r) * 1024 + k0 + tx] = f2bf(t[tx][ty * 4 + r]);
}

// ---------- rel tables prep: rel_k -> bf16 [1025][64]; rel_v -> rvT [64][1040] ----------
__global__ void k_relprep(const float* __restrict__ rk, const float* __restrict__ rv,
                          unsigned short* __restrict__ relkb, unsigned short* __restrict__ rvTb) {
  int b = blockIdx.x;
  if (b < 33) {
    int i = (b * 256 + threadIdx.x) * 8;
    if (i < 65600) {
      float4 a = *(const float4*)(rk + i);
      float4 c = *(const float4*)(rk + i + 4);
      s16x8 o;
      o[0] = (short)f2bf(a.x); o[1] = (short)f2bf(a.y); o[2] = (short)f2bf(a.z); o[3] = (short)f2bf(a.w);
      o[4] = (short)f2bf(c.x); o[5] = (short)f2bf(c.y); o[6] = (short)f2bf(c.z); o[7] = (short)f2bf(c.w);
      *(s16x8*)(relkb + i) = o;
    }
  } else {
    int i = (b - 33) * 256 + threadIdx.x;
    if (i < 65600) {
      int p = i >> 6, d = i & 63;
      rvTb[d * 1040 + p] = f2bf(rv[i]);
    }
  }
}

// ---------- per-head V transpose: vbuf [bh][s][d] -> vT [bh][d][s] ----------
__global__ __launch_bounds__(256)
void k_trV(const unsigned short* __restrict__ v, unsigned short* __restrict__ vt) {
  __shared__ unsigned short T[64][72];
  const int tid = threadIdx.x;
  const int bh = blockIdx.x >> 4;
  const int s0 = (blockIdx.x & 15) << 6;
  const int r = tid >> 2, cb = (tid & 3) << 4;
  const unsigned short* src = v + ((size_t)bh << 16) + (size_t)(s0 + r) * 64 + cb;
  *(s16x8*)&T[r][cb] = *(const s16x8*)src;
  *(s16x8*)&T[r][cb + 8] = *(const s16x8*)(src + 8);
  __syncthreads();
  unsigned short* dst = vt + ((size_t)bh << 16) + (size_t)r * 1024 + s0 + cb;
  s16x8 o0, o1;
#pragma unroll
  for (int e = 0; e < 8; ++e) o0[e] = T[cb + e][r];
#pragma unroll
  for (int e = 0; e < 8; ++e) o1[e] = T[cb + 8 + e][r];
  *(s16x8*)dst = o0;
  *(s16x8*)(dst + 8) = o1;
}

// ---------- bf16 GEMM: C[4096x1024] = A[4096x1024] @ BT[1024x1024]^T + bias ----------
template <int MODE>
__global__ __launch_bounds__(256, 2)
void k_gemm(const unsigned short* __restrict__ A, const unsigned short* __restrict__ BT,
            const float* __restrict__ bias, void* __restrict__ Cout) {
  __shared__ alignas(16) unsigned short aT[2][4096];
  __shared__ alignas(16) unsigned short bT[2][2048];
  const int tid = threadIdx.x;
  const int lane = tid & 63;
  const int l15 = lane & 15, lhi = lane >> 4;
  const int w = tid >> 6;
  const int wr = w * 32;
  const int brow = blockIdx.y * 128, bcol = blockIdx.x * 64;
  f32x4 acc[2][4] = {};

#define STAGE(buf, kt) do {                                                              \
    int k0s = (kt) * 32;                                                                 \
    {                                                                                    \
      int c = tid;                                                                       \
      int row = c >> 2, k8 = (c & 3) * 8;                                                \
      __builtin_amdgcn_global_load_lds(                                                  \
        (const __attribute__((address_space(1))) void*)(A + (size_t)(brow + row) * 1024 + k0s + k8), \
        (__attribute__((address_space(3))) void*)(&aT[buf][c * 8]), 16, 0, 0);           \
      __builtin_amdgcn_global_load_lds(                                                  \
        (const __attribute__((address_space(1))) void*)(BT + (size_t)(bcol + row) * 1024 + k0s + k8),\
        (__attribute__((address_space(3))) void*)(&bT[buf][c * 8]), 16, 0, 0);           \
    }                                                                                    \
    {                                                                                    \
      int c = tid + 256;                                                                 \
      int row = c >> 2, k8 = (c & 3) * 8;                                                \
      __builtin_amdgcn_global_load_lds(                                                  \
        (const __attribute__((address_space(1))) void*)(A + (size_t)(brow + row) * 1024 + k0s + k8), \
        (__attribute__((address_space(3))) void*)(&aT[buf][c * 8]), 16, 0, 0);           \
    }                                                                                    \
  } while (0)

  int cur = 0;
  STAGE(0, 0);
  for (int kt = 0; kt < 32; ++kt) {
    __syncthreads();
    if (kt + 1 < 32) STAGE(cur ^ 1, kt + 1);
    s16x8 af[2], bfv[4];
#pragma unroll
    for (int m = 0; m < 2; ++m)
      af[m] = *(const s16x8*)&aT[cur][(wr + m * 16 + l15) * 32 + lhi * 8];
#pragma unroll
    for (int n = 0; n < 4; ++n)
      bfv[n] = *(const s16x8*)&bT[cur][(n * 16 + l15) * 32 + lhi * 8];
#pragma unroll
    for (int m = 0; m < 2; ++m)
#pragma unroll
      for (int n = 0; n < 4; ++n)
        acc[m][n] = MFMA16(af[m], bfv[n], acc[m][n], 0, 0, 0);
    __syncthreads();
    cur ^= 1;
  }
#undef STAGE

#pragma unroll
  for (int m = 0; m < 2; ++m) {
#pragma unroll
    for (int n = 0; n < 4; ++n) {
      int col = bcol + n * 16 + l15;
      float bs = bias[col];
#pragma unroll
      for (int j = 0; j < 4; ++j) {
        int r = brow + wr + m * 16 + lhi * 4 + j;
        float v = acc[m][n][j] + bs;
        if (MODE == 0) {
          int b = r >> 10, s = r & 1023, h = col >> 6, d = col & 63;
          ((unsigned short*)Cout)[(((size_t)((b << 4) + h) * 1024 + s) << 6) + d] = f2bf(v);
        } else {
          ((float*)Cout)[(size_t)r * 1024 + col] = v;
        }
      }
    }
  }
}

// ---------- fused attention ----------
#define RPW 1032   // pbuf row stride (elems); 2064 B
#define PWP 520    // Tb / pw row stride (elems); 1040 B

__global__ __launch_bounds__(256, 3)
void k_attn(const unsigned short* __restrict__ qb, const unsigned short* __restrict__ kbm,
            const unsigned short* __restrict__ vT, const unsigned short* __restrict__ relk,
            const unsigned short* __restrict__ rvT, float* __restrict__ attn_out,
            unsigned short* __restrict__ xscr) {
  __shared__ alignas(16) unsigned short pbuf[16 * RPW];   // 33,024 B unnormalized exp
  __shared__ alignas(16) unsigned short TbPw[16 * PWP];   // 16,640 B rel-table, later pw
  __shared__ float red[4][16];
  __shared__ float izS[16], plS[16], phS[16];
  __shared__ unsigned short bndS[32];                     // [0:16) G[qi][0], [16:32) G[qi][1024]

  const int tid = threadIdx.x;
  const int lane = tid & 63;
  const int w = tid >> 6;
  const int l15 = lane & 15, lhi = lane >> 4;
  // XCD-aware swizzle: XCD x owns heads [x*8, x*8+8)
  const int orig = ((blockIdx.x & 7) << 9) | (blockIdx.x >> 3);
  const int bh = orig >> 6;
  const int q0 = (orig & 63) << 4;

  const unsigned short* Qh = qb + ((size_t)bh << 16);
  const unsigned short* Kh = kbm + ((size_t)bh << 16);
  const unsigned short* Vth = vT + ((size_t)bh << 16);

  const unsigned short* qp = Qh + (size_t)(q0 + l15) * 64 + lhi * 8;
  s16x8 qa0 = *(const s16x8*)qp;
  s16x8 qa1 = *(const s16x8*)(qp + 32);

  // ---- boundary dots: bndS = Qtile . relk[0] and Qtile . relk[1024] ----
  {
    int sel = (l15 == 1) ? 1024 : 0;
    const unsigned short* rp = relk + (size_t)sel * 64 + lhi * 8;
    s16x8 rb0 = *(const s16x8*)rp;
    s16x8 rb1 = *(const s16x8*)(rp + 32);
    f32x4 d = {0.f, 0.f, 0.f, 0.f};
    d = MFMA16(qa0, rb0, d, 0, 0, 0);
    d = MFMA16(qa1, rb1, d, 0, 0, 0);
    if (l15 < 2) {
#pragma unroll
      for (int j = 0; j < 4; ++j) bndS[l15 * 16 + lhi * 4 + j] = f2bf(d[j]);
    }
  }

  // ---- pass 1 (two 512-k halves): build rel-table Tb, then e = exp((qk+rel)/8) ----
  float zp = 0.f;
  for (int half = 0; half < 2; ++half) {
    const int khalf = half << 9;
    __syncthreads();   // bndS ready (half 0) / prior hot-loop reads of TbPw done (half 1)

    // fill: Tb[row][u] = (u < fl ? bndlo : bndhi); valid interior overwritten by scatter
    for (int i = tid; i < 16 * 64; i += 256) {
      int row = i >> 6, c8 = (i & 63) << 3;
      int fl = q0 + row - khalf - 512;   // u < fl -> low-clip region
      unsigned short vlo = bndS[row], vhi = bndS[16 + row];
      s16x8 o;
#pragma unroll
      for (int e = 0; e < 8; ++e) o[e] = (short)((c8 + e < fl) ? vlo : vhi);
      *(s16x8*)&TbPw[row * PWP + c8] = o;
    }
    __syncthreads();

    // scatter: MFMA sweep over valid p-tiles; Tb[qi][u] = Qtile[qi].relk[p], u = p-khalf+q0+qi-512
    {
      int pmin = khalf - q0 + 497;
      int PT0 = (pmin < 0 ? 0 : pmin) & ~15;
      int PT1 = khalf - q0 + 1023; if (PT1 > 1024) PT1 = 1024;
      for (int pt = PT0 + w * 16; pt <= PT1; pt += 64) {
        int pr = pt + l15; if (pr > 1024) pr = 1024;
        const unsigned short* rp = relk + (size_t)pr * 64 + lhi * 8;
        s16x8 rf0 = *(const s16x8*)rp;
        s16x8 rf1 = *(const s16x8*)(rp + 32);
        f32x4 d = {0.f, 0.f, 0.f, 0.f};
        d = MFMA16(qa0, rf0, d, 0, 0, 0);
        d = MFMA16(qa1, rf1, d, 0, 0, 0);
#pragma unroll
        for (int j = 0; j < 4; ++j) {
          int qi = lhi * 4 + j;
          int p = pt + l15;
          int u = p - khalf + q0 + qi - 512;
          if (p <= 1024 && u >= 0 && u < 512) TbPw[qi * PWP + u] = f2bf(d[j]);
        }
      }
    }
    __syncthreads();

    // hot loop: swapped MFMA(K,Q) -> lane owns 4 consecutive k for q=l15
    for (int n = 0; n < 8; ++n) {
      const int ktile = khalf + w * 16 + n * 64;
      const unsigned short* kp = Kh + (size_t)(ktile + l15) * 64 + lhi * 8;
      s16x8 kf0 = *(const s16x8*)kp;
      s16x8 kf1 = *(const s16x8*)(kp + 32);
      f32x4 c = {0.f, 0.f, 0.f, 0.f};
      __builtin_amdgcn_s_setprio(1);
      c = MFMA16(kf0, qa0, c, 0, 0, 0);
      c = MFMA16(kf1, qa1, c, 0, 0, 0);
      __builtin_amdgcn_s_setprio(0);
      uint2 tv = *(const uint2*)&TbPw[l15 * PWP + (ktile - khalf) + lhi * 4];
      float t0 = bf2f((unsigned short)(tv.x & 0xFFFF));
      float t1 = bf2f((unsigned short)(tv.x >> 16));
      float t2 = bf2f((unsigned short)(tv.y & 0xFFFF));
      float t3 = bf2f((unsigned short)(tv.y >> 16));
      float e0 = __expf((c[0] + t0) * 0.125f);
      float e1 = __expf((c[1] + t1) * 0.125f);
      float e2 = __expf((c[2] + t2) * 0.125f);
      float e3 = __expf((c[3] + t3) * 0.125f);
      zp += (e0 + e1) + (e2 + e3);
      uint2 pk;
      pk.x = (unsigned int)f2bf(e0) | ((unsigned int)f2bf(e1) << 16);
      pk.y = (unsigned int)f2bf(e2) | ((unsigned int)f2bf(e3) << 16);
      *(uint2*)&pbuf[l15 * RPW + ktile + lhi * 4] = pk;
    }
  }

  // ---- Z reduction: sum across lhi groups (same q=l15), then across waves ----
  zp += __shfl_xor(zp, 16, 64);
  zp += __shfl_xor(zp, 32, 64);
  if (lane < 16) red[w][lane] = zp;
  __syncthreads();   // pbuf + red complete
  if (tid < 16)
    izS[tid] = 1.0f / (red[0][tid] + red[1][tid] + red[2][tid] + red[3][tid]);

  // ---- clip-mass post-pass: plS (k <= qa-512) or phS (k >= qa+512) ----
  {
    const int qi = tid >> 4, tq = tid & 15;
    const int qa = q0 + qi;
    int lo, hi;
    const bool isPh = (qa < 512);
    if (isPh) { lo = qa + 512; hi = 1024; }
    else      { lo = 0;        hi = qa - 511; }
    float s = 0.f;
    const unsigned short* srow = pbuf + qi * RPW;
    const int kb0 = lo & ~7;
    for (int k8 = kb0 + tq * 8; k8 < hi; k8 += 128) {
      s16x8 v8 = *(const s16x8*)&srow[k8];
#pragma unroll
      for (int e = 0; e < 8; ++e) {
        int k = k8 + e;
        s += (k >= lo && k < hi) ? bf2f((unsigned short)v8[e]) : 0.f;
      }
    }
#pragma unroll
    for (int off = 1; off < 16; off <<= 1) s += __shfl_xor(s, off, 64);
    if (tq == 0) { plS[qi] = isPh ? 0.f : s; phS[qi] = isPh ? s : 0.f; }
  }
  __syncthreads();   // izS, plS, phS ready

  // ---- normalized attn -> d_out (f32, b128 LDS reads, contiguous NT stores) ----
  {
    float* ao = attn_out + ((size_t)bh << 20) + ((size_t)q0 << 10);
#pragma unroll
    for (int n = 0; n < 8; ++n) {
      int row = (tid >> 7) + n * 2;
      int c8 = (tid & 127) << 3;
      float iz = izS[row];
      s16x8 p8 = *(const s16x8*)&pbuf[row * RPW + c8];
      f32x4 o0, o1;
      o0[0] = bf2f((unsigned short)p8[0]) * iz; o0[1] = bf2f((unsigned short)p8[1]) * iz;
      o0[2] = bf2f((unsigned short)p8[2]) * iz; o0[3] = bf2f((unsigned short)p8[3]) * iz;
      o1[0] = bf2f((unsigned short)p8[4]) * iz; o1[1] = bf2f((unsigned short)p8[5]) * iz;
      o1[2] = bf2f((unsigned short)p8[6]) * iz; o1[3] = bf2f((unsigned short)p8[7]) * iz;
      __builtin_nontemporal_store(o0, (f32x4*)(ao + (row << 10) + c8));
      __builtin_nontemporal_store(o1, (f32x4*)(ao + (row << 10) + c8 + 4));
    }
  }

  // ---- PV: acc[q][d] += p . V  (V^T from global/L2, no LDS, no syncs) ----
  f32x4 acc = {0.f, 0.f, 0.f, 0.f};
  const int d0w = w << 4;
  const unsigned short* vrow = Vth + (size_t)(d0w + l15) * 1024 + lhi * 8;
#pragma unroll 8
  for (int kc = 0; kc < 1024; kc += 32) {
    s16x8 pa = *(const s16x8*)&pbuf[l15 * RPW + kc + lhi * 8];
    s16x8 vf = *(const s16x8*)(vrow + kc);
    acc = MFMA16(pa, vf, acc, 0, 0, 0);
  }

  // ---- rel_v GEMM over globally-sheared p (two 512-halves, vector-shift staging) ----
  const unsigned short* rrow = rvT + (size_t)(d0w + l15) * 1040 + lhi * 8;
  {
    const int sqi = tid >> 4, stq = tid & 15;
    const int ssh = sqi & 7, shs = ssh >> 1;
    const bool sodd = (ssh & 1) != 0;
    unsigned short* drow = TbPw + sqi * PWP;
    const unsigned short* srow = pbuf + sqi * RPW;
    for (int ph = 0; ph < 2; ++ph) {
      __syncthreads();
      const int base = q0 + sqi + (ph ? 0 : -512);
      for (int t = stq; t < 64; t += 16) {
        const int kw0 = base + t * 8;
        s16x8 o;
        if (kw0 >= 0 && kw0 + 8 <= 1024) {
          const int A = kw0 - ssh;            // multiple of 8, >= 0
          union { s16x8 v; unsigned int u[4]; } a0, a1, ov;
          a0.v = *(const s16x8*)&srow[A];
          a1.v = *(const s16x8*)&srow[A + 8];
          unsigned int wd[8];
#pragma unroll
          for (int j2 = 0; j2 < 4; ++j2) { wd[j2] = a0.u[j2]; wd[4 + j2] = a1.u[j2]; }
          unsigned int v7[7];
#pragma unroll
          for (int j2 = 0; j2 < 7; ++j2) {
            unsigned int sf = (wd[j2] >> 16) | (wd[j2 + 1] << 16);
            v7[j2] = sodd ? sf : wd[j2];
          }
#pragma unroll
          for (int j2 = 0; j2 < 4; ++j2) {
            unsigned int t0 = (shs & 1) ? v7[j2 + 1] : v7[j2];
            unsigned int t1 = (shs & 1) ? v7[j2 + 3] : v7[j2 + 2];
            ov.u[j2] = (shs & 2) ? t1 : t0;
          }
          o = ov.v;
        } else if (kw0 + 8 <= 0 || kw0 >= 1024) {
          o = (s16x8){0, 0, 0, 0, 0, 0, 0, 0};
        } else {
#pragma unroll
          for (int e = 0; e < 8; ++e) {
            int k = kw0 + e;
            int kc2 = k < 0 ? 0 : (k > 1023 ? 1023 : k);
            unsigned short vv = srow[kc2];
            o[e] = (k >= 0 && k < 1024) ? (short)vv : (short)0;
          }
        }
        *(s16x8*)&drow[t * 8] = o;
        if (ph == 0 && t == 0) drow[0] = f2bf(plS[sqi]);  // p=0 carries clip-low mass
      }
      __syncthreads();
#pragma unroll 8
      for (int kc = 0; kc < 512; kc += 32) {
        s16x8 pa = *(const s16x8*)&TbPw[l15 * PWP + kc + lhi * 8];
        s16x8 rb = *(const s16x8*)(rrow + (ph << 9) + kc);
        acc = MFMA16(pa, rb, acc, 0, 0, 0);
      }
    }
  }

  // ---- epilogue: + phigh * rel_v[1024], scale by iz, scrambled bf16 store ----
  float rv1024 = bf2f(rvT[(size_t)(d0w + l15) * 1040 + 1024]);
  const size_t fb = ((size_t)(bh >> 2) << 18) + ((size_t)(bh & 3) << 6);
#pragma unroll
  for (int j = 0; j < 4; ++j) {
    int qi = lhi * 4 + j;
    float v = (acc[j] + phS[qi] * rv1024) * izS[qi];
    xscr[fb + ((size_t)(q0 + qi) << 8) + d0w + l15] = f2bf(v);
  }
}

extern "C" void kernel_launch(void* const* d_in, const int* in_sizes, int n_in,
                              void* d_out, int out_size, void* d_ws, size_t ws_size,
                              hipStream_t stream) {
  (void)in_sizes; (void)n_in; (void)out_size; (void)ws_size;
  const float* query = (const float*)d_in[0];
  const float* key   = (const float*)d_in[1];
  const float* value = (const float*)d_in[2];
  const float* Wq = (const float*)d_in[3];
  const float* bq = (const float*)d_in[4];
  const float* Wk = (const float*)d_in[5];
  const float* bk = (const float*)d_in[6];
  const float* Wv = (const float*)d_in[7];
  const float* bv = (const float*)d_in[8];
  const float* Wo = (const float*)d_in[9];
  const float* bo = (const float*)d_in[10];
  const float* rel_k = (const float*)d_in[11];
  const float* rel_v = (const float*)d_in[12];

  char* ws = (char*)d_ws;
  const size_t MB = 1024 * 1024;
  unsigned short* qb    = (unsigned short*)(ws);            //  8 MB [64][1024][64]
  unsigned short* kbuf  = (unsigned short*)(ws + 8 * MB);   //  8 MB
  unsigned short* vbuf  = (unsigned short*)(ws + 16 * MB);  //  8 MB (dead after k_trV -> xscr)
  unsigned short* tmp16 = (unsigned short*)(ws + 24 * MB);  //  8 MB (cvt input; later vT)
  unsigned short* wt    = (unsigned short*)(ws + 32 * MB);  //  2 MB (current W^T)
  unsigned short* relkb = (unsigned short*)(ws + 34 * MB);  //  ~0.13 MB
  unsigned short* rvTb  = (unsigned short*)(ws + 34 * MB + 512 * 1024);  // ~0.13 MB
  unsigned short* vTb   = tmp16;                            // reuse
  unsigned short* xscr  = vbuf;                             // reuse

  float* out0 = (float*)d_out;
  float* attn_out = out0 + 4194304;

  dim3 trb(32, 8), trg(32, 32);
  dim3 gg(16, 32);

  k_relprep<<<290, 256, 0, stream>>>(rel_k, rel_v, relkb, rvTb);

  k_cvt_bf16<<<2048, 256, 0, stream>>>(query, tmp16, 4194304);
  k_tr1024<<<trg, trb, 0, stream>>>(Wq, wt);
  k_gemm<0><<<gg, 256, 0, stream>>>(tmp16, wt, bq, qb);

  k_cvt_bf16<<<2048, 256, 0, stream>>>(key, tmp16, 4194304);
  k_tr1024<<<trg, trb, 0, stream>>>(Wk, wt);
  k_gemm<0><<<gg, 256, 0, stream>>>(tmp16, wt, bk, kbuf);

  k_cvt_bf16<<<2048, 256, 0, stream>>>(value, tmp16, 4194304);
  k_tr1024<<<trg, trb, 0, stream>>>(Wv, wt);
  k_gemm<0><<<gg, 256, 0, stream>>>(tmp16, wt, bv, vbuf);

  k_trV<<<1024, 256, 0, stream>>>(vbuf, vTb);       // vbuf -> vT (tmp16 region)
  k_tr1024<<<trg, trb, 0, stream>>>(Wo, wt);

  // fused attention: attn (f32) -> d_out; pre-scrambled X (bf16) -> xscr (vbuf region)
  k_attn<<<4096, 256, 0, stream>>>(qb, kbuf, vTb, relkb, rvTb, attn_out, xscr);

  // output projection (f32 out)
  k_gemm<1><<<gg, 256, 0, stream>>>(xscr, wt, bo, out0);
}